// Round 1
// baseline (453.606 us; speedup 1.0000x reference)
//
#include <hip/hip_runtime.h>

typedef unsigned short u16;
typedef __bf16 bf16x8 __attribute__((ext_vector_type(8)));
typedef float f32x4 __attribute__((ext_vector_type(4)));
typedef unsigned int u32x4 __attribute__((ext_vector_type(4)));
typedef unsigned int u32x2 __attribute__((ext_vector_type(2)));

__device__ __forceinline__ u16 f2b(float f) {
  union { float f; unsigned u; } v; v.f = f;
  return (u16)((v.u + 0x7fffu + ((v.u >> 16) & 1u)) >> 16);
}

__device__ __forceinline__ bf16x8 ldfrag(const u16* p) {
  u32x4 r = *(const u32x4*)p;
  return __builtin_bit_cast(bf16x8, r);
}

#define GLOAD_LDS16(gp, lp)                                                        \
  __builtin_amdgcn_global_load_lds((const __attribute__((address_space(1))) void*)(gp), \
                                   (__attribute__((address_space(3))) void*)(lp), 16, 0, 0)

#define MFMA16(a, b, c) __builtin_amdgcn_mfma_f32_16x16x32_bf16((a), (b), (c), 0, 0, 0)

// ---------------- pack kernels ----------------

__global__ __launch_bounds__(256) void k_pack_x(const float* __restrict__ x,
                                                u16* __restrict__ xb) {
  int i = (blockIdx.x * 256 + threadIdx.x) * 4;
  float4 v = *(const float4*)(x + i);
  u32x2 o;
  o[0] = (unsigned)f2b(v.x) | ((unsigned)f2b(v.y) << 16);
  o[1] = (unsigned)f2b(v.z) | ((unsigned)f2b(v.w) << 16);
  *(u32x2*)(xb + i) = o;
}

// Wq/Wk/Wv [16][1024][64] fp32 -> wt [3072][1024] bf16, wt[p*1024+h*64+e][d] = W[p][h][d][e]
__global__ __launch_bounds__(256) void k_pack_w(const float* __restrict__ Wq,
                                                const float* __restrict__ Wk,
                                                const float* __restrict__ Wv,
                                                u16* __restrict__ wt) {
  __shared__ u16 tile[64][65];
  int bid = blockIdx.x;
  int p = bid >> 8, rem = bid & 255, h = rem >> 4, dt = rem & 15;
  const float* W = (p == 0) ? Wq : (p == 1) ? Wk : Wv;
  int tid = threadIdx.x;
  for (int i = tid; i < 4096; i += 256) {
    int d = i >> 6, e = i & 63;
    tile[e][d] = f2b(W[h * 65536 + (dt * 64 + d) * 64 + e]);
  }
  __syncthreads();
  for (int i = tid; i < 4096; i += 256) {
    int e = i >> 6, d = i & 63;
    wt[(size_t)(p * 1024 + h * 64 + e) * 1024 + dt * 64 + d] = tile[e][d];
  }
}

// Wo [1024][1024] fp32 -> wt [1024][1024] bf16 transposed: wt[n][k] = Wo[k][n]
__global__ __launch_bounds__(256) void k_pack_wo(const float* __restrict__ Wo,
                                                 u16* __restrict__ wt) {
  __shared__ u16 tile[64][65];
  int kt = blockIdx.x >> 4, nt = blockIdx.x & 15;
  int tid = threadIdx.x;
  for (int i = tid; i < 4096; i += 256) {
    int dk = i >> 6, de = i & 63;
    tile[de][dk] = f2b(Wo[(size_t)(kt * 64 + dk) * 1024 + nt * 64 + de]);
  }
  __syncthreads();
  for (int i = tid; i < 4096; i += 256) {
    int de = i >> 6, dk = i & 63;
    wt[(size_t)(nt * 64 + de) * 1024 + kt * 64 + dk] = tile[de][dk];
  }
}

// ---------------- shared GEMM core: 128x128 tile, BK=32, K=1024, A[M][K], Bt[N][K] ----------------

__device__ __forceinline__ void gemm_core(const u16* __restrict__ A, const u16* __restrict__ Bt,
                                          int row0, int col0, u16* As, u16* Bs, f32x4 acc[4][4]) {
  const int tid = threadIdx.x, w = tid >> 6, lane = tid & 63;
  const int quad = lane >> 4, l15 = lane & 15;
  const int wm = (w >> 1) * 64, wn = (w & 1) * 64;
  for (int k0 = 0; k0 < 1024; k0 += 32) {
#pragma unroll
    for (int i = 0; i < 2; i++) {
      int bse = (w * 2 + i) * 512;
      int flat = bse + lane * 8;
      int r = flat >> 5, c = flat & 31;
      GLOAD_LDS16(A + (size_t)(row0 + r) * 1024 + k0 + c, As + bse);
      GLOAD_LDS16(Bt + (size_t)(col0 + r) * 1024 + k0 + c, Bs + bse);
    }
    __syncthreads();
    bf16x8 af[4], bfr[4];
#pragma unroll
    for (int t = 0; t < 4; t++) {
      af[t] = ldfrag(As + (wm + t * 16 + l15) * 32 + quad * 8);
      bfr[t] = ldfrag(Bs + (wn + t * 16 + l15) * 32 + quad * 8);
    }
#pragma unroll
    for (int mt = 0; mt < 4; mt++)
#pragma unroll
      for (int nt = 0; nt < 4; nt++)
        acc[mt][nt] = MFMA16(af[mt], bfr[nt], acc[mt][nt]);
    __syncthreads();
  }
}

// ---------------- GEMM1: qkv projection ----------------

__global__ __launch_bounds__(256) void k_gemm_qkv(const u16* __restrict__ xb, const u16* __restrict__ wt,
                                                  const float* __restrict__ bq, const float* __restrict__ bk,
                                                  const float* __restrict__ bv,
                                                  u16* __restrict__ qo, u16* __restrict__ ko,
                                                  u16* __restrict__ vto) {
  __shared__ u16 As[4096], Bs[4096];
  f32x4 acc[4][4];
  const f32x4 z4 = {0.f, 0.f, 0.f, 0.f};
#pragma unroll
  for (int a = 0; a < 4; a++)
#pragma unroll
    for (int b = 0; b < 4; b++) acc[a][b] = z4;
  const int row0 = blockIdx.x * 128, col0 = blockIdx.y * 128;
  gemm_core(xb, wt, row0, col0, As, Bs, acc);
  const int tid = threadIdx.x, w = tid >> 6, lane = tid & 63;
  const int quad = lane >> 4, l15 = lane & 15;
  const int wm = (w >> 1) * 64, wn = (w & 1) * 64;
#pragma unroll
  for (int nt = 0; nt < 4; nt++) {
    int c = col0 + wn + nt * 16 + l15;
    int p = c >> 10, rem = c & 1023;
    int h = rem >> 6, e = rem & 63;
    const float* bias = (p == 0) ? bq : (p == 1) ? bk : bv;
    float bval = bias[rem];
#pragma unroll
    for (int mt = 0; mt < 4; mt++) {
#pragma unroll
      for (int reg = 0; reg < 4; reg++) {
        int r = row0 + wm + mt * 16 + quad * 4 + reg;
        int b_ = r >> 11, s = r & 2047;
        int bh = b_ * 16 + h;
        u16 o = f2b(acc[mt][nt][reg] + bval);
        if (p == 0)
          qo[((size_t)bh * 2048 + s) * 64 + e] = o;
        else if (p == 1)
          ko[((size_t)bh * 2048 + s) * 64 + e] = o;
        else
          vto[((size_t)bh * 64 + e) * 2048 + s] = o;
      }
    }
  }
}

// ---------------- GEMM2: output projection ----------------

__global__ __launch_bounds__(256) void k_gemm_out(const u16* __restrict__ zb, const u16* __restrict__ wt,
                                                  const float* __restrict__ bo, float* __restrict__ out) {
  __shared__ u16 As[4096], Bs[4096];
  f32x4 acc[4][4];
  const f32x4 z4 = {0.f, 0.f, 0.f, 0.f};
#pragma unroll
  for (int a = 0; a < 4; a++)
#pragma unroll
    for (int b = 0; b < 4; b++) acc[a][b] = z4;
  const int row0 = blockIdx.x * 128, col0 = blockIdx.y * 128;
  gemm_core(zb, wt, row0, col0, As, Bs, acc);
  const int tid = threadIdx.x, w = tid >> 6, lane = tid & 63;
  const int quad = lane >> 4, l15 = lane & 15;
  const int wm = (w >> 1) * 64, wn = (w & 1) * 64;
#pragma unroll
  for (int nt = 0; nt < 4; nt++) {
    int c = col0 + wn + nt * 16 + l15;
    float bval = bo[c];
#pragma unroll
    for (int mt = 0; mt < 4; mt++) {
#pragma unroll
      for (int reg = 0; reg < 4; reg++) {
        int r = row0 + wm + mt * 16 + quad * 4 + reg;
        out[(size_t)r * 1024 + c] = acc[mt][nt][reg] + bval;
      }
    }
  }
}

// ---------------- flash attention ----------------
// grid (32 qtiles, 64 bh); 256 threads = 4 waves x 16 q-rows; 64-key chunks.

__global__ __launch_bounds__(256) void k_attn(const u16* __restrict__ q, const u16* __restrict__ k,
                                              const u16* __restrict__ vt, u16* __restrict__ z) {
  __shared__ u16 Ks[64 * 72], Vs[64 * 72], Ps[4 * 16 * 72];
  const int tid = threadIdx.x, w = tid >> 6, lane = tid & 63;
  const int quad = lane >> 4, l15 = lane & 15;
  const int bh = blockIdx.y, s0 = blockIdx.x * 64;
  const size_t base = (size_t)bh * 2048 * 64;
  const f32x4 z4 = {0.f, 0.f, 0.f, 0.f};

  const u16* qp = q + base + (size_t)(s0 + w * 16 + l15) * 64 + quad * 8;
  bf16x8 qf0 = ldfrag(qp), qf1 = ldfrag(qp + 32);

  float m_i[4], l_i[4];
  f32x4 acc[4];
#pragma unroll
  for (int i = 0; i < 4; i++) { m_i[i] = -3.0e38f; l_i[i] = 0.f; acc[i] = z4; }

  for (int kc = 0; kc < 2048; kc += 64) {
#pragma unroll
    for (int i = 0; i < 2; i++) {
      int f = (tid + i * 256) * 8;
      int r = f >> 6, cc = f & 63;
      *(u32x4*)&Ks[r * 72 + cc] = *(const u32x4*)(k + base + (size_t)(kc + r) * 64 + cc);
      *(u32x4*)&Vs[r * 72 + cc] = *(const u32x4*)(vt + base + (size_t)r * 2048 + kc + cc);
    }
    __syncthreads();

    f32x4 sc[4];
#pragma unroll
    for (int nt = 0; nt < 4; nt++) {
      bf16x8 b0 = ldfrag(&Ks[(nt * 16 + l15) * 72 + quad * 8]);
      bf16x8 b1 = ldfrag(&Ks[(nt * 16 + l15) * 72 + 32 + quad * 8]);
      sc[nt] = MFMA16(qf0, b0, z4);
      sc[nt] = MFMA16(qf1, b1, sc[nt]);
    }
    float alpha[4];
#pragma unroll
    for (int reg = 0; reg < 4; reg++) {
      float v0 = sc[0][reg] * 0.125f, v1 = sc[1][reg] * 0.125f;
      float v2 = sc[2][reg] * 0.125f, v3 = sc[3][reg] * 0.125f;
      float mx = fmaxf(fmaxf(v0, v1), fmaxf(v2, v3));
      mx = fmaxf(mx, __shfl_xor(mx, 1));
      mx = fmaxf(mx, __shfl_xor(mx, 2));
      mx = fmaxf(mx, __shfl_xor(mx, 4));
      mx = fmaxf(mx, __shfl_xor(mx, 8));
      float mnew = fmaxf(m_i[reg], mx);
      alpha[reg] = __expf(m_i[reg] - mnew);
      float p0 = __expf(v0 - mnew), p1 = __expf(v1 - mnew);
      float p2 = __expf(v2 - mnew), p3 = __expf(v3 - mnew);
      sc[0][reg] = p0; sc[1][reg] = p1; sc[2][reg] = p2; sc[3][reg] = p3;
      float sm = p0 + p1 + p2 + p3;
      sm += __shfl_xor(sm, 1);
      sm += __shfl_xor(sm, 2);
      sm += __shfl_xor(sm, 4);
      sm += __shfl_xor(sm, 8);
      l_i[reg] = l_i[reg] * alpha[reg] + sm;
      m_i[reg] = mnew;
    }
#pragma unroll
    for (int dt = 0; dt < 4; dt++)
#pragma unroll
      for (int reg = 0; reg < 4; reg++) acc[dt][reg] *= alpha[reg];
#pragma unroll
    for (int nt = 0; nt < 4; nt++)
#pragma unroll
      for (int reg = 0; reg < 4; reg++)
        Ps[(w * 16 + quad * 4 + reg) * 72 + nt * 16 + l15] = f2b(sc[nt][reg]);
    __syncthreads();

    bf16x8 a0 = ldfrag(&Ps[(w * 16 + l15) * 72 + quad * 8]);
    bf16x8 a1 = ldfrag(&Ps[(w * 16 + l15) * 72 + 32 + quad * 8]);
#pragma unroll
    for (int dt = 0; dt < 4; dt++) {
      bf16x8 b0 = ldfrag(&Vs[(dt * 16 + l15) * 72 + quad * 8]);
      bf16x8 b1 = ldfrag(&Vs[(dt * 16 + l15) * 72 + 32 + quad * 8]);
      acc[dt] = MFMA16(a0, b0, acc[dt]);
      acc[dt] = MFMA16(a1, b1, acc[dt]);
    }
    __syncthreads();
  }
  const int b_ = bh >> 4, h = bh & 15;
  float inv[4];
#pragma unroll
  for (int reg = 0; reg < 4; reg++) inv[reg] = 1.f / l_i[reg];
#pragma unroll
  for (int dt = 0; dt < 4; dt++)
#pragma unroll
    for (int reg = 0; reg < 4; reg++) {
      int s = s0 + w * 16 + quad * 4 + reg;
      int e = dt * 16 + l15;
      z[((size_t)(b_ * 2048 + s)) * 1024 + h * 64 + e] = f2b(acc[dt][reg] * inv[reg]);
    }
}

// ---------------- launcher ----------------

extern "C" void kernel_launch(void* const* d_in, const int* in_sizes, int n_in,
                              void* d_out, int out_size, void* d_ws, size_t ws_size,
                              hipStream_t stream) {
  (void)in_sizes; (void)n_in; (void)out_size;
  const float* x  = (const float*)d_in[0];
  const float* Wq = (const float*)d_in[1];
  const float* bq = (const float*)d_in[2];
  const float* Wk = (const float*)d_in[3];
  const float* bk = (const float*)d_in[4];
  const float* Wv = (const float*)d_in[5];
  const float* bv = (const float*)d_in[6];
  const float* Wo = (const float*)d_in[7];
  const float* bo = (const float*)d_in[8];
  float* out = (float*)d_out;
  char* ws = (char*)d_ws;
  if (ws_size < 92274688u) return;  // need ~92 MB scratch

  u16* xb   = (u16*)(ws + 0);          // 8192x1024 bf16          (16 MiB)
  u16* wqkv = (u16*)(ws + 16777216);   // 3072x1024 bf16 (Bt)     (6 MiB)
  u16* wo_t = (u16*)(ws + 23068672);   // 1024x1024 bf16 (Bt)     (2 MiB)
  u16* qb   = (u16*)(ws + 25165824);   // [bh][s][e]              (16 MiB)
  u16* kb   = (u16*)(ws + 41943040);   // [bh][s][e]              (16 MiB)
  u16* vtb  = (u16*)(ws + 58720256);   // [bh][e][s]              (16 MiB)
  u16* zb   = (u16*)(ws + 75497472);   // multi_head [8192][1024] (16 MiB)

  k_pack_x<<<8192, 256, 0, stream>>>(x, xb);
  k_pack_w<<<768, 256, 0, stream>>>(Wq, Wk, Wv, wqkv);
  k_pack_wo<<<256, 256, 0, stream>>>(Wo, wo_t);
  k_gemm_qkv<<<dim3(64, 24), 256, 0, stream>>>(xb, wqkv, bq, bk, bv, qb, kb, vtb);
  k_attn<<<dim3(32, 64), 256, 0, stream>>>(qb, kb, vtb, zb);
  k_gemm_out<<<dim3(64, 8), 256, 0, stream>>>(zb, wo_t, bo, out);
}

// Round 2
// 351.649 us; speedup vs baseline: 1.2899x; 1.2899x over previous
//
#include <hip/hip_runtime.h>

typedef unsigned short u16;
typedef __bf16 bf16x8 __attribute__((ext_vector_type(8)));
typedef float f32x4 __attribute__((ext_vector_type(4)));
typedef float f32x16 __attribute__((ext_vector_type(16)));
typedef unsigned int u32x4 __attribute__((ext_vector_type(4)));
typedef unsigned int u32x2 __attribute__((ext_vector_type(2)));

__device__ __forceinline__ u16 f2b(float f) {
  union { float f; unsigned u; } v; v.f = f;
  return (u16)((v.u + 0x7fffu + ((v.u >> 16) & 1u)) >> 16);
}

__device__ __forceinline__ unsigned pkbf(float a, float b) {
#if __has_builtin(__builtin_amdgcn_cvt_pk_bf16_f32)
  typedef __bf16 bf16x2v __attribute__((ext_vector_type(2)));
  bf16x2v r = __builtin_amdgcn_cvt_pk_bf16_f32(a, b);
  return __builtin_bit_cast(unsigned, r);
#else
  return (unsigned)f2b(a) | ((unsigned)f2b(b) << 16);
#endif
}

__device__ __forceinline__ float fexp2(float x) {
#if __has_builtin(__builtin_amdgcn_exp2f)
  return __builtin_amdgcn_exp2f(x);
#else
  return exp2f(x);
#endif
}

__device__ __forceinline__ bf16x8 ldfrag(const u16* p) {
  u32x4 r = *(const u32x4*)p;
  return __builtin_bit_cast(bf16x8, r);
}

#define GLOAD_LDS16(gp, lp)                                                        \
  __builtin_amdgcn_global_load_lds((const __attribute__((address_space(1))) void*)(gp), \
                                   (__attribute__((address_space(3))) void*)(lp), 16, 0, 0)

#define MFMA16(a, b, c) __builtin_amdgcn_mfma_f32_16x16x32_bf16((a), (b), (c), 0, 0, 0)
#define MFMA32(a, b, c) __builtin_amdgcn_mfma_f32_32x32x16_bf16((a), (b), (c), 0, 0, 0)

// ---------------- pack kernels ----------------

__global__ __launch_bounds__(256) void k_pack_x(const float* __restrict__ x,
                                                u16* __restrict__ xb) {
  int i = (blockIdx.x * 256 + threadIdx.x) * 4;
  float4 v = *(const float4*)(x + i);
  u32x2 o;
  o[0] = pkbf(v.x, v.y);
  o[1] = pkbf(v.z, v.w);
  *(u32x2*)(xb + i) = o;
}

// Wq/Wk/Wv [16][1024][64] fp32 -> wt [3072][1024] bf16, wt[p*1024+h*64+e][d] = W[p][h][d][e]
__global__ __launch_bounds__(256) void k_pack_w(const float* __restrict__ Wq,
                                                const float* __restrict__ Wk,
                                                const float* __restrict__ Wv,
                                                u16* __restrict__ wt) {
  __shared__ u16 tile[64][65];
  int bid = blockIdx.x;
  int p = bid >> 8, rem = bid & 255, h = rem >> 4, dt = rem & 15;
  const float* W = (p == 0) ? Wq : (p == 1) ? Wk : Wv;
  int tid = threadIdx.x;
  for (int i = tid; i < 4096; i += 256) {
    int d = i >> 6, e = i & 63;
    tile[e][d] = f2b(W[h * 65536 + (dt * 64 + d) * 64 + e]);
  }
  __syncthreads();
  for (int i = tid; i < 4096; i += 256) {
    int e = i >> 6, d = i & 63;
    wt[(size_t)(p * 1024 + h * 64 + e) * 1024 + dt * 64 + d] = tile[e][d];
  }
}

// Wo [1024][1024] fp32 -> wt [1024][1024] bf16 transposed: wt[n][k] = Wo[k][n]
__global__ __launch_bounds__(256) void k_pack_wo(const float* __restrict__ Wo,
                                                 u16* __restrict__ wt) {
  __shared__ u16 tile[64][65];
  int kt = blockIdx.x >> 4, nt = blockIdx.x & 15;
  int tid = threadIdx.x;
  for (int i = tid; i < 4096; i += 256) {
    int dk = i >> 6, de = i & 63;
    tile[de][dk] = f2b(Wo[(size_t)(kt * 64 + dk) * 1024 + nt * 64 + de]);
  }
  __syncthreads();
  for (int i = tid; i < 4096; i += 256) {
    int de = i >> 6, dk = i & 63;
    wt[(size_t)(nt * 64 + de) * 1024 + kt * 64 + dk] = tile[de][dk];
  }
}

// ---------------- shared GEMM core: 128x128 tile, BK=32, K=1024, A[M][K], Bt[N][K] ----------------

__device__ __forceinline__ void gemm_core(const u16* __restrict__ A, const u16* __restrict__ Bt,
                                          int row0, int col0, u16* As, u16* Bs, f32x4 acc[4][4]) {
  const int tid = threadIdx.x, w = tid >> 6, lane = tid & 63;
  const int quad = lane >> 4, l15 = lane & 15;
  const int wm = (w >> 1) * 64, wn = (w & 1) * 64;
  for (int k0 = 0; k0 < 1024; k0 += 32) {
#pragma unroll
    for (int i = 0; i < 2; i++) {
      int bse = (w * 2 + i) * 512;
      int flat = bse + lane * 8;
      int r = flat >> 5, c = flat & 31;
      GLOAD_LDS16(A + (size_t)(row0 + r) * 1024 + k0 + c, As + bse);
      GLOAD_LDS16(Bt + (size_t)(col0 + r) * 1024 + k0 + c, Bs + bse);
    }
    __syncthreads();
    bf16x8 af[4], bfr[4];
#pragma unroll
    for (int t = 0; t < 4; t++) {
      af[t] = ldfrag(As + (wm + t * 16 + l15) * 32 + quad * 8);
      bfr[t] = ldfrag(Bs + (wn + t * 16 + l15) * 32 + quad * 8);
    }
#pragma unroll
    for (int mt = 0; mt < 4; mt++)
#pragma unroll
      for (int nt = 0; nt < 4; nt++)
        acc[mt][nt] = MFMA16(af[mt], bfr[nt], acc[mt][nt]);
    __syncthreads();
  }
}

// ---------------- GEMM1: qkv projection ----------------

__global__ __launch_bounds__(256) void k_gemm_qkv(const u16* __restrict__ xb, const u16* __restrict__ wt,
                                                  const float* __restrict__ bq, const float* __restrict__ bk,
                                                  const float* __restrict__ bv,
                                                  u16* __restrict__ qo, u16* __restrict__ ko,
                                                  u16* __restrict__ vto) {
  __shared__ u16 As[4096], Bs[4096];
  f32x4 acc[4][4];
  const f32x4 z4 = {0.f, 0.f, 0.f, 0.f};
#pragma unroll
  for (int a = 0; a < 4; a++)
#pragma unroll
    for (int b = 0; b < 4; b++) acc[a][b] = z4;
  const int row0 = blockIdx.x * 128, col0 = blockIdx.y * 128;
  gemm_core(xb, wt, row0, col0, As, Bs, acc);
  const int tid = threadIdx.x, w = tid >> 6, lane = tid & 63;
  const int quad = lane >> 4, l15 = lane & 15;
  const int wm = (w >> 1) * 64, wn = (w & 1) * 64;
#pragma unroll
  for (int nt = 0; nt < 4; nt++) {
    int c = col0 + wn + nt * 16 + l15;
    int p = c >> 10, rem = c & 1023;
    int h = rem >> 6, e = rem & 63;
    const float* bias = (p == 0) ? bq : (p == 1) ? bk : bv;
    float bval = bias[rem];
#pragma unroll
    for (int mt = 0; mt < 4; mt++) {
#pragma unroll
      for (int reg = 0; reg < 4; reg++) {
        int r = row0 + wm + mt * 16 + quad * 4 + reg;
        int b_ = r >> 11, s = r & 2047;
        int bh = b_ * 16 + h;
        u16 o = f2b(acc[mt][nt][reg] + bval);
        if (p == 0)
          qo[((size_t)bh * 2048 + s) * 64 + e] = o;
        else if (p == 1)
          ko[((size_t)bh * 2048 + s) * 64 + e] = o;
        else
          vto[((size_t)bh * 64 + e) * 2048 + s] = o;
      }
    }
  }
}

// ---------------- GEMM2: output projection ----------------

__global__ __launch_bounds__(256) void k_gemm_out(const u16* __restrict__ zb, const u16* __restrict__ wt,
                                                  const float* __restrict__ bo, float* __restrict__ out) {
  __shared__ u16 As[4096], Bs[4096];
  f32x4 acc[4][4];
  const f32x4 z4 = {0.f, 0.f, 0.f, 0.f};
#pragma unroll
  for (int a = 0; a < 4; a++)
#pragma unroll
    for (int b = 0; b < 4; b++) acc[a][b] = z4;
  const int row0 = blockIdx.x * 128, col0 = blockIdx.y * 128;
  gemm_core(zb, wt, row0, col0, As, Bs, acc);
  const int tid = threadIdx.x, w = tid >> 6, lane = tid & 63;
  const int quad = lane >> 4, l15 = lane & 15;
  const int wm = (w >> 1) * 64, wn = (w & 1) * 64;
#pragma unroll
  for (int nt = 0; nt < 4; nt++) {
    int c = col0 + wn + nt * 16 + l15;
    float bval = bo[c];
#pragma unroll
    for (int mt = 0; mt < 4; mt++) {
#pragma unroll
      for (int reg = 0; reg < 4; reg++) {
        int r = row0 + wm + mt * 16 + quad * 4 + reg;
        out[(size_t)r * 1024 + c] = acc[mt][nt][reg] + bval;
      }
    }
  }
}

// ---------------- flash attention (S^T / acc^T formulation, 32x32x16 MFMA) ----------------
// grid (16 qtiles of 128 rows, 64 bh); 256 threads = 4 waves x 32 q-rows; 64-key chunks.
// Per lane: q-row = lane&31 (hi half = lane>>5 splits K-dim of fragments).
// S^T = K.Q^T  (A=K frag, B=Q frag)  -> C layout: col = qrow, rows = keys.
// acc^T = V^T.P^T (A=V^T frag, B=P^T frag) -> C layout: col = qrow, rows = e.

__global__ __launch_bounds__(256) void k_attn(const u16* __restrict__ q, const u16* __restrict__ k,
                                              const u16* __restrict__ vt, u16* __restrict__ z) {
  __shared__ u16 Ks[64 * 72], Vs[64 * 72], Ps[4][32 * 72];
  const int tid = threadIdx.x, w = tid >> 6, lane = tid & 63;
  const int l31 = lane & 31, hi = lane >> 5;
  const int bh = blockIdx.y, s0 = blockIdx.x * 128;
  const size_t base = (size_t)bh * 2048 * 64;
  const int qrow = s0 + w * 32 + l31;
  const float C2 = 0.18033688f;  // 0.125 * log2(e)

  // Q fragments (B operand): B[k=d][n=qrow], lane holds n=l31, k=hi*8+j (+16*ks)
  bf16x8 qf[4];
  {
    const u16* qp = q + base + (size_t)qrow * 64 + hi * 8;
#pragma unroll
    for (int ks = 0; ks < 4; ks++) qf[ks] = ldfrag(qp + ks * 16);
  }

  f32x16 accT[2];
#pragma unroll
  for (int et = 0; et < 2; et++)
#pragma unroll
    for (int r = 0; r < 16; r++) accT[et][r] = 0.f;
  float m_i = -3.0e38f, l_i = 0.f;

  // K/V staging: each thread stages 2x16B of K and 2x16B of V per chunk.
  const int srow = tid >> 3;          // 0..31
  const int scol = (tid & 7) * 8;     // 0..56
  const u16* kg = k + base;
  const u16* vg = vt + base;

  u32x4 kr0, kr1, vr0, vr1;
  kr0 = *(const u32x4*)(kg + (size_t)srow * 64 + scol);
  kr1 = *(const u32x4*)(kg + (size_t)(srow + 32) * 64 + scol);
  vr0 = *(const u32x4*)(vg + (size_t)srow * 2048 + scol);
  vr1 = *(const u32x4*)(vg + (size_t)(srow + 32) * 2048 + scol);

  u16* Pw = Ps[w];

  for (int kc = 0; kc < 2048; kc += 64) {
    __syncthreads();  // previous chunk's LDS reads complete
    *(u32x4*)&Ks[srow * 72 + scol] = kr0;
    *(u32x4*)&Ks[(srow + 32) * 72 + scol] = kr1;
    *(u32x4*)&Vs[srow * 72 + scol] = vr0;
    *(u32x4*)&Vs[(srow + 32) * 72 + scol] = vr1;
    __syncthreads();
    if (kc + 64 < 2048) {  // prefetch next chunk (overlaps compute)
      int kn = kc + 64;
      kr0 = *(const u32x4*)(kg + (size_t)(kn + srow) * 64 + scol);
      kr1 = *(const u32x4*)(kg + (size_t)(kn + srow + 32) * 64 + scol);
      vr0 = *(const u32x4*)(vg + (size_t)srow * 2048 + kn + scol);
      vr1 = *(const u32x4*)(vg + (size_t)(srow + 32) * 2048 + kn + scol);
    }

    // S^T: two 32-key tiles
    f32x16 sc[2];
#pragma unroll
    for (int t = 0; t < 2; t++) {
#pragma unroll
      for (int r = 0; r < 16; r++) sc[t][r] = 0.f;
#pragma unroll
      for (int ks = 0; ks < 4; ks++) {
        bf16x8 kf = ldfrag(&Ks[(t * 32 + l31) * 72 + ks * 16 + hi * 8]);
        sc[t] = MFMA32(kf, qf[ks], sc[t]);
      }
    }

    // online softmax (per-lane scalar state; one q-row per lane)
    float mx = sc[0][0];
#pragma unroll
    for (int t = 0; t < 2; t++)
#pragma unroll
      for (int r = 0; r < 16; r++) mx = fmaxf(mx, sc[t][r]);
    mx = fmaxf(mx, __shfl_xor(mx, 32));
    float mnew = fmaxf(m_i, mx);
    float alpha = fexp2(C2 * (m_i - mnew));
    float mC = mnew * C2;
    float sm = 0.f;
#pragma unroll
    for (int t = 0; t < 2; t++)
#pragma unroll
      for (int r = 0; r < 16; r++) {
        float p = fexp2(sc[t][r] * C2 - mC);
        sc[t][r] = p;
        sm += p;
      }
    sm += __shfl_xor(sm, 32);
    l_i = l_i * alpha + sm;
    m_i = mnew;
#pragma unroll
    for (int et = 0; et < 2; et++)
#pragma unroll
      for (int r = 0; r < 16; r++) accT[et][r] *= alpha;

    // pack P -> LDS: lane holds keys t*32 + r4*8 + hi*4 + (0..3) for qrow=l31
#pragma unroll
    for (int t = 0; t < 2; t++)
#pragma unroll
      for (int r4 = 0; r4 < 4; r4++) {
        u32x2 d;
        d[0] = pkbf(sc[t][r4 * 4 + 0], sc[t][r4 * 4 + 1]);
        d[1] = pkbf(sc[t][r4 * 4 + 2], sc[t][r4 * 4 + 3]);
        *(u32x2*)&Pw[l31 * 72 + t * 32 + r4 * 8 + hi * 4] = d;
      }
    // no barrier: P round-trip stays within this wave

    // PV: acc^T += V^T . P^T  over 4 K=16 slabs
#pragma unroll
    for (int ks = 0; ks < 4; ks++) {
      bf16x8 pf = ldfrag(&Pw[l31 * 72 + ks * 16 + hi * 8]);
#pragma unroll
      for (int et = 0; et < 2; et++) {
        bf16x8 vf = ldfrag(&Vs[(et * 32 + l31) * 72 + ks * 16 + hi * 8]);
        accT[et] = MFMA32(vf, pf, accT[et]);
      }
    }
  }

  // epilogue: acc^T C-layout: row e_local = (r&3)+8*(r>>2)+4*hi, col qrow=l31
  const int b_ = bh >> 4, h = bh & 15;
  float inv = 1.f / l_i;
  u16* zr = z + ((size_t)(b_ * 2048 + qrow)) * 1024 + h * 64;
#pragma unroll
  for (int et = 0; et < 2; et++)
#pragma unroll
    for (int rr = 0; rr < 16; rr += 2) {
      unsigned pkd = pkbf(accT[et][rr] * inv, accT[et][rr + 1] * inv);
      int e = et * 32 + (rr & 3) + 8 * (rr >> 2) + 4 * hi;
      *(unsigned*)&zr[e] = pkd;
    }
}

// ---------------- launcher ----------------

extern "C" void kernel_launch(void* const* d_in, const int* in_sizes, int n_in,
                              void* d_out, int out_size, void* d_ws, size_t ws_size,
                              hipStream_t stream) {
  (void)in_sizes; (void)n_in; (void)out_size;
  const float* x  = (const float*)d_in[0];
  const float* Wq = (const float*)d_in[1];
  const float* bq = (const float*)d_in[2];
  const float* Wk = (const float*)d_in[3];
  const float* bk = (const float*)d_in[4];
  const float* Wv = (const float*)d_in[5];
  const float* bv = (const float*)d_in[6];
  const float* Wo = (const float*)d_in[7];
  const float* bo = (const float*)d_in[8];
  float* out = (float*)d_out;
  char* ws = (char*)d_ws;
  if (ws_size < 92274688u) return;  // need ~92 MB scratch

  u16* xb   = (u16*)(ws + 0);          // 8192x1024 bf16          (16 MiB)
  u16* wqkv = (u16*)(ws + 16777216);   // 3072x1024 bf16 (Bt)     (6 MiB)
  u16* wo_t = (u16*)(ws + 23068672);   // 1024x1024 bf16 (Bt)     (2 MiB)
  u16* qb   = (u16*)(ws + 25165824);   // [bh][s][e]              (16 MiB)
  u16* kb   = (u16*)(ws + 41943040);   // [bh][s][e]              (16 MiB)
  u16* vtb  = (u16*)(ws + 58720256);   // [bh][e][s]              (16 MiB)
  u16* zb   = (u16*)(ws + 75497472);   // multi_head [8192][1024] (16 MiB)

  k_pack_x<<<8192, 256, 0, stream>>>(x, xb);
  k_pack_w<<<768, 256, 0, stream>>>(Wq, Wk, Wv, wqkv);
  k_pack_wo<<<256, 256, 0, stream>>>(Wo, wo_t);
  k_gemm_qkv<<<dim3(64, 24), 256, 0, stream>>>(xb, wqkv, bq, bk, bv, qb, kb, vtb);
  k_attn<<<dim3(16, 64), 256, 0, stream>>>(qb, kb, vtb, zb);
  k_gemm_out<<<dim3(64, 8), 256, 0, stream>>>(zb, wo_t, bo, out);
}